// Round 12
// baseline (120.569 us; speedup 1.0000x reference)
//
#include <hip/hip_runtime.h>

// Vanilla RNN B=4096 S=512 I=1 H=16 O=1 — serial-chain latency optimization.
// Lane = (row, h-row); 16 lanes per batch (DPP row). Wall time =
// 512 * per-step critical path.
//
// R11 = R7's STEP **verbatim** (last proven-good: pass 3.05e-5, ~36 µs)
// + two-way batch interleave shell. R9/R10 failed with bit-identical
// absmax 8.789e-3 across different binaries => deterministic defect in
// the R8-style asm head (XT/wih inside asm, a0=bias init), NOT a DPP
// timing hazard. This round bisects: per-batch math is byte-identical to
// R7 (XP = fmaf(x,wih,bias) outside the asm, a0 tied-init to XP, s_nop 1,
// 17-operand list); only the shell changes (512 blocks, P/Q sets,
// alternating STEPs, dual epilogue). P's tree/exp/rcp tail is plain SSA
// and can sink past Q's asm-volatile front -> latency overlap.
//
// g-trick: state g = 1/(2^s+1), h = 1-2g; rowsum(W_hh) folds into bias,
// -2*S2LE into weights; S2LE = 2*log2(e) pre-scales for exp2.
// Weights self-calibrated to the HW row_ror permutation (R1/R7-validated).
// Loads: R6 staged blocks, modulo-2 named buffers, no per-iter vmcnt drain.

#define S2LE 2.8853900817779268f  // 2*log2(e)

typedef float float4_ __attribute__((ext_vector_type(4)));

#define ROTI(v, N) __builtin_amdgcn_mov_dpp((v), 0x120 + (N), 0xF, 0xF, 0)
#define ROTF(v, N) __int_as_float(__builtin_amdgcn_mov_dpp(__float_as_int(v), 0x120 + (N), 0xF, 0xF, 0))

__global__ __launch_bounds__(64) void rnn_kernel(
    const float* __restrict__ x,
    const float* __restrict__ W_ih,
    const float* __restrict__ W_hh,
    const float* __restrict__ b_ih,
    const float* __restrict__ b_hh,
    const float* __restrict__ W_fc,
    const float* __restrict__ b_fc,
    float* __restrict__ out)
{
    const int l  = (int)threadIdx.x;
    const int li = l & 15;          // h-row
    const int r  = l >> 4;          // DPP row = batch slot within set
    const int bb = (int)blockIdx.x * 8;

    const float* __restrict__ row = W_hh + li * 16;

    float sw = 0.0f;
#pragma unroll
    for (int j = 0; j < 16; ++j) sw += row[j];

    const float wsc = -2.0f * S2LE;

    // Self-calibrated weights: w[N] = wsc * W[li][sigma_N(li)], sigma_N =
    // HW row_ror:N permutation (validated end-to-end R1/R7). Shared by P/Q.
    float w0  = wsc * row[li];
    float w1  = wsc * row[ROTI(li, 1)];
    float w2  = wsc * row[ROTI(li, 2)];
    float w3  = wsc * row[ROTI(li, 3)];
    float w4  = wsc * row[ROTI(li, 4)];
    float w5  = wsc * row[ROTI(li, 5)];
    float w6  = wsc * row[ROTI(li, 6)];
    float w7  = wsc * row[ROTI(li, 7)];
    float w8  = wsc * row[ROTI(li, 8)];
    float w9  = wsc * row[ROTI(li, 9)];
    float w10 = wsc * row[ROTI(li, 10)];
    float w11 = wsc * row[ROTI(li, 11)];
    float w12 = wsc * row[ROTI(li, 12)];
    float w13 = wsc * row[ROTI(li, 13)];
    float w14 = wsc * row[ROTI(li, 14)];
    float w15 = wsc * row[ROTI(li, 15)];

    const float wih  = W_ih[li] * S2LE;
    const float bias = (b_ih[li] + b_hh[li] + sw) * S2LE;
    const float wfc  = W_fc[li];
    const float bfc  = b_fc[0];

    // Set P: batches bb+0..3 ; set Q: batches bb+4..7 (rows 0..3 each).
    const float4_* __restrict__ xvP = (const float4_*)(x + (size_t)(bb + r) * 512);
    const float4_* __restrict__ xvQ = (const float4_*)(x + (size_t)(bb + 4 + r) * 512);

    float gP = 0.5f, gQ = 0.5f;  // h = 0

    // ===== R7's STEP, verbatim, parameterized only by the g register =====
#define STEP(G, XP) do { \
    float a0 = (XP), a1, a2, a3; \
    asm volatile( \
        "s_nop 1\n\t" \
        "v_fmac_f32 %0, %4, %5\n\t" \
        "v_mul_f32_dpp %1, %4, %9  row_ror:4  row_mask:0xf bank_mask:0xf\n\t" \
        "v_mul_f32_dpp %2, %4, %13 row_ror:8  row_mask:0xf bank_mask:0xf\n\t" \
        "v_mul_f32_dpp %3, %4, %17 row_ror:12 row_mask:0xf bank_mask:0xf\n\t" \
        "v_fmac_f32_dpp %0, %4, %6  row_ror:1  row_mask:0xf bank_mask:0xf\n\t" \
        "v_fmac_f32_dpp %1, %4, %10 row_ror:5  row_mask:0xf bank_mask:0xf\n\t" \
        "v_fmac_f32_dpp %2, %4, %14 row_ror:9  row_mask:0xf bank_mask:0xf\n\t" \
        "v_fmac_f32_dpp %3, %4, %18 row_ror:13 row_mask:0xf bank_mask:0xf\n\t" \
        "v_fmac_f32_dpp %0, %4, %7  row_ror:2  row_mask:0xf bank_mask:0xf\n\t" \
        "v_fmac_f32_dpp %1, %4, %11 row_ror:6  row_mask:0xf bank_mask:0xf\n\t" \
        "v_fmac_f32_dpp %2, %4, %15 row_ror:10 row_mask:0xf bank_mask:0xf\n\t" \
        "v_fmac_f32_dpp %3, %4, %19 row_ror:14 row_mask:0xf bank_mask:0xf\n\t" \
        "v_fmac_f32_dpp %0, %4, %8  row_ror:3  row_mask:0xf bank_mask:0xf\n\t" \
        "v_fmac_f32_dpp %1, %4, %12 row_ror:7  row_mask:0xf bank_mask:0xf\n\t" \
        "v_fmac_f32_dpp %2, %4, %16 row_ror:11 row_mask:0xf bank_mask:0xf\n\t" \
        "v_fmac_f32_dpp %3, %4, %20 row_ror:15 row_mask:0xf bank_mask:0xf\n\t" \
        : "+v"(a0), "=&v"(a1), "=&v"(a2), "=&v"(a3) \
        : "v"(G), \
          "v"(w0),  "v"(w1),  "v"(w2),  "v"(w3), \
          "v"(w4),  "v"(w5),  "v"(w6),  "v"(w7), \
          "v"(w8),  "v"(w9),  "v"(w10), "v"(w11), \
          "v"(w12), "v"(w13), "v"(w14), "v"(w15)); \
    float s_ = (a0 + a1) + (a2 + a3); \
    float e_ = __builtin_amdgcn_exp2f(s_); \
    G = __builtin_amdgcn_rcpf(e_ + 1.0f); \
} while (0)

// Interleave at step granularity: P's tail (plain SSA) can sink past Q's
// asm front and vice versa; XP fmas are x-only and hoistable.
#define BLOCK(BP, BQ) do { \
    _Pragma("unroll") \
    for (int j = 0; j < 2; ++j) { \
        STEP(gP, fmaf((BP)[j][0], wih, bias)); \
        STEP(gQ, fmaf((BQ)[j][0], wih, bias)); \
        STEP(gP, fmaf((BP)[j][1], wih, bias)); \
        STEP(gQ, fmaf((BQ)[j][1], wih, bias)); \
        STEP(gP, fmaf((BP)[j][2], wih, bias)); \
        STEP(gQ, fmaf((BQ)[j][2], wih, bias)); \
        STEP(gP, fmaf((BP)[j][3], wih, bias)); \
        STEP(gQ, fmaf((BQ)[j][3], wih, bias)); \
    } \
} while (0)

    float4_ bPA[2], bPB[2], bQA[2], bQB[2];
#pragma unroll
    for (int j = 0; j < 2; ++j) { bPA[j] = xvP[j]; bQA[j] = xvQ[j]; }

    // Modulo-2 pipeline over 64 blocks of 8 timesteps (per set): loads
    // issue one full block ahead; named buffers, no per-iter vmcnt drain.
#pragma unroll 1
    for (int i = 0; i < 64; i += 2) {
#pragma unroll
        for (int j = 0; j < 2; ++j) {
            bPB[j] = xvP[(2 * (i + 1) + j) & 127];
            bQB[j] = xvQ[(2 * (i + 1) + j) & 127];
        }
        BLOCK(bPA, bQA);
#pragma unroll
        for (int j = 0; j < 2; ++j) {
            bPA[j] = xvP[(2 * (i + 2) + j) & 127];
            bQA[j] = xvQ[(2 * (i + 2) + j) & 127];
        }
        BLOCK(bPB, bQB);
    }
#undef BLOCK
#undef STEP

    // out[b] = sum_i wfc_i*h_i + bfc, h = 1-2g; rotation-reduce per row.
    float pP = fmaf(-2.0f * wfc, gP, wfc);
    float pQ = fmaf(-2.0f * wfc, gQ, wfc);
    pP += ROTF(pP, 8);  pQ += ROTF(pQ, 8);
    pP += ROTF(pP, 4);  pQ += ROTF(pQ, 4);
    pP += ROTF(pP, 2);  pQ += ROTF(pQ, 2);
    pP += ROTF(pP, 1);  pQ += ROTF(pQ, 1);
    if (li == 0) {
        out[bb + r]     = pP + bfc;
        out[bb + 4 + r] = pQ + bfc;
    }
}

extern "C" void kernel_launch(void* const* d_in, const int* in_sizes, int n_in,
                              void* d_out, int out_size, void* d_ws, size_t ws_size,
                              hipStream_t stream) {
    const float* x    = (const float*)d_in[0];
    const float* W_ih = (const float*)d_in[1];
    const float* W_hh = (const float*)d_in[2];
    const float* b_ih = (const float*)d_in[3];
    const float* b_hh = (const float*)d_in[4];
    const float* W_fc = (const float*)d_in[5];
    const float* b_fc = (const float*)d_in[6];
    float* out = (float*)d_out;

    rnn_kernel<<<512, 64, 0, stream>>>(x, W_ih, W_hh, b_ih, b_hh, W_fc, b_fc, out);
}

// Round 13
// 92.765 us; speedup vs baseline: 1.2997x; 1.2997x over previous
//
#include <hip/hip_runtime.h>

// Vanilla RNN B=4096 S=512 I=1 H=16 O=1 — serial-chain latency optimization.
// Lane = (batch, h-row); 16 lanes/batch; 1024 waves = 1 wave/SIMD, one
// serial chain per SIMD. Wall = 512 * (F + T) per chain, independent of
// wave packing (R11 measured: 2 chains/wave at half the waves = exactly
// 2x wall). F = front issue span ~75-85 cyc, T = tree+exp+rcp ~90 cyc.
//
// R12 = R7 (champion: pass 3.05e-5, ~36 µs kernel) with the asm matvec
// as 2 interleaved accumulator chains of depth 8 instead of 4x4:
// reduction tree 2 hops -> 1 hop, -2 instructions. Hazard-proven head
// kept verbatim (s_nop 1, a0 tied to XP computed OUTSIDE the asm, plain
// fmac before the first DPP read of g — R8/R9-style head restructure is
// the known 8.8e-3 corruption, never do it). Same-chain fmacs are 2
// instrs apart (~6 cyc) >= fmac dep latency.
//
// g-trick: state g = 1/(2^s+1), h = 1-2g; rowsum(W_hh) folds into bias,
// -2*S2LE into weights; S2LE = 2*log2(e) pre-scales for exp2.
// Weights self-calibrated to the HW row_ror permutation (R1/R7-validated).
// Loads: R6 staged blocks, modulo-2 named buffers, no per-iter vmcnt drain.

#define S2LE 2.8853900817779268f  // 2*log2(e)

typedef float float4_ __attribute__((ext_vector_type(4)));

#define ROTI(v, N) __builtin_amdgcn_mov_dpp((v), 0x120 + (N), 0xF, 0xF, 0)
#define ROTF(v, N) __int_as_float(__builtin_amdgcn_mov_dpp(__float_as_int(v), 0x120 + (N), 0xF, 0xF, 0))

__global__ __launch_bounds__(64) void rnn_kernel(
    const float* __restrict__ x,
    const float* __restrict__ W_ih,
    const float* __restrict__ W_hh,
    const float* __restrict__ b_ih,
    const float* __restrict__ b_hh,
    const float* __restrict__ W_fc,
    const float* __restrict__ b_fc,
    float* __restrict__ out)
{
    const int li = (int)(threadIdx.x & 15u);
    const int b  = (int)((blockIdx.x * 64u + threadIdx.x) >> 4);

    const float* __restrict__ row = W_hh + li * 16;

    float sw = 0.0f;
#pragma unroll
    for (int j = 0; j < 16; ++j) sw += row[j];

    const float wsc = -2.0f * S2LE;

    // Self-calibrated weights: w[N] = wsc * W[li][sigma_N(li)], sigma_N =
    // the HW's row_ror:N permutation (validated end-to-end R1/R7).
    float w0  = wsc * row[li];
    float w1  = wsc * row[ROTI(li, 1)];
    float w2  = wsc * row[ROTI(li, 2)];
    float w3  = wsc * row[ROTI(li, 3)];
    float w4  = wsc * row[ROTI(li, 4)];
    float w5  = wsc * row[ROTI(li, 5)];
    float w6  = wsc * row[ROTI(li, 6)];
    float w7  = wsc * row[ROTI(li, 7)];
    float w8  = wsc * row[ROTI(li, 8)];
    float w9  = wsc * row[ROTI(li, 9)];
    float w10 = wsc * row[ROTI(li, 10)];
    float w11 = wsc * row[ROTI(li, 11)];
    float w12 = wsc * row[ROTI(li, 12)];
    float w13 = wsc * row[ROTI(li, 13)];
    float w14 = wsc * row[ROTI(li, 14)];
    float w15 = wsc * row[ROTI(li, 15)];

    const float wih  = W_ih[li] * S2LE;
    const float bias = (b_ih[li] + b_hh[li] + sw) * S2LE;
    const float wfc  = W_fc[li];
    const float bfc  = b_fc[0];

    const float4_* __restrict__ xv = (const float4_*)(x + (size_t)b * 512);

    float g = 0.5f;  // represents h = 0

    // One step: R7 head (s_nop 1, tied a0=XP, plain fmac first), then 2
    // interleaved DPP-fmac chains of depth 8; single tree add; exp2-
    // sigmoid tail (best measured: R5 poly +93, R8 newton +17 cyc/step).
#define STEP(XP) do { \
    float a0 = (XP), a1; \
    asm volatile( \
        "s_nop 1\n\t" \
        "v_fmac_f32 %0, %2, %3\n\t" \
        "v_mul_f32_dpp %1, %2, %11  row_ror:8  row_mask:0xf bank_mask:0xf\n\t" \
        "v_fmac_f32_dpp %0, %2, %4  row_ror:1  row_mask:0xf bank_mask:0xf\n\t" \
        "v_fmac_f32_dpp %1, %2, %12 row_ror:9  row_mask:0xf bank_mask:0xf\n\t" \
        "v_fmac_f32_dpp %0, %2, %5  row_ror:2  row_mask:0xf bank_mask:0xf\n\t" \
        "v_fmac_f32_dpp %1, %2, %13 row_ror:10 row_mask:0xf bank_mask:0xf\n\t" \
        "v_fmac_f32_dpp %0, %2, %6  row_ror:3  row_mask:0xf bank_mask:0xf\n\t" \
        "v_fmac_f32_dpp %1, %2, %14 row_ror:11 row_mask:0xf bank_mask:0xf\n\t" \
        "v_fmac_f32_dpp %0, %2, %7  row_ror:4  row_mask:0xf bank_mask:0xf\n\t" \
        "v_fmac_f32_dpp %1, %2, %15 row_ror:12 row_mask:0xf bank_mask:0xf\n\t" \
        "v_fmac_f32_dpp %0, %2, %8  row_ror:5  row_mask:0xf bank_mask:0xf\n\t" \
        "v_fmac_f32_dpp %1, %2, %16 row_ror:13 row_mask:0xf bank_mask:0xf\n\t" \
        "v_fmac_f32_dpp %0, %2, %9  row_ror:6  row_mask:0xf bank_mask:0xf\n\t" \
        "v_fmac_f32_dpp %1, %2, %17 row_ror:14 row_mask:0xf bank_mask:0xf\n\t" \
        "v_fmac_f32_dpp %0, %2, %10 row_ror:7  row_mask:0xf bank_mask:0xf\n\t" \
        "v_fmac_f32_dpp %1, %2, %18 row_ror:15 row_mask:0xf bank_mask:0xf\n\t" \
        : "+v"(a0), "=&v"(a1) \
        : "v"(g), \
          "v"(w0),  "v"(w1),  "v"(w2),  "v"(w3), \
          "v"(w4),  "v"(w5),  "v"(w6),  "v"(w7), \
          "v"(w8),  "v"(w9),  "v"(w10), "v"(w11), \
          "v"(w12), "v"(w13), "v"(w14), "v"(w15)); \
    float s_ = a0 + a1; \
    float e_ = __builtin_amdgcn_exp2f(s_); \
    g = __builtin_amdgcn_rcpf(e_ + 1.0f); \
} while (0)

// 16 recurrent steps from a 4-x-float4 staged block.
#define BLOCK(BUF) do { \
    _Pragma("unroll") \
    for (int j = 0; j < 4; ++j) { \
        STEP(fmaf((BUF)[j][0], wih, bias)); \
        STEP(fmaf((BUF)[j][1], wih, bias)); \
        STEP(fmaf((BUF)[j][2], wih, bias)); \
        STEP(fmaf((BUF)[j][3], wih, bias)); \
    } \
} while (0)

    float4_ bufA[4], bufB[4];
#pragma unroll
    for (int j = 0; j < 4; ++j) bufA[j] = xv[j];  // block 0

    // Unroll-2 modulo pipeline over 32 blocks of 16 timesteps (R6): loads
    // issue one full block ahead; no register rotation, no per-iter drain.
#pragma unroll 1
    for (int i = 0; i < 32; i += 2) {
#pragma unroll
        for (int j = 0; j < 4; ++j) bufB[j] = xv[(4 * (i + 1) + j) & 127];
        BLOCK(bufA);
#pragma unroll
        for (int j = 0; j < 4; ++j) bufA[j] = xv[(4 * (i + 2) + j) & 127];
        BLOCK(bufB);
    }
#undef BLOCK
#undef STEP

    // out[b] = sum_i wfc_i * h_i + bfc,  h = 1 - 2g (f32 g).
    float p = fmaf(-2.0f * wfc, g, wfc);
    p += ROTF(p, 8);
    p += ROTF(p, 4);
    p += ROTF(p, 2);
    p += ROTF(p, 1);
    if (li == 0) out[b] = p + bfc;
}

extern "C" void kernel_launch(void* const* d_in, const int* in_sizes, int n_in,
                              void* d_out, int out_size, void* d_ws, size_t ws_size,
                              hipStream_t stream) {
    const float* x    = (const float*)d_in[0];
    const float* W_ih = (const float*)d_in[1];
    const float* W_hh = (const float*)d_in[2];
    const float* b_ih = (const float*)d_in[3];
    const float* b_hh = (const float*)d_in[4];
    const float* W_fc = (const float*)d_in[5];
    const float* b_fc = (const float*)d_in[6];
    float* out = (float*)d_out;

    rnn_kernel<<<1024, 64, 0, stream>>>(x, W_ih, W_hh, b_ih, b_hh, W_fc, b_fc, out);
}